// Round 5
// baseline (173.494 us; speedup 1.0000x reference)
//
#include <hip/hip_runtime.h>

// ---------------- types / helpers ----------------
typedef __attribute__((ext_vector_type(16))) float f32x16;
typedef __attribute__((ext_vector_type(8))) __bf16 bf16x8;
typedef __attribute__((ext_vector_type(8))) unsigned short u16x8;

__device__ __forceinline__ unsigned short f2bf(float f) {
    unsigned int u = __float_as_uint(f);
    u += 0x7fffu + ((u >> 16) & 1u);       // RTNE
    return (unsigned short)(u >> 16);
}

__device__ __forceinline__ float softplus_f(float x) {
    // max(x,0) + log2(1+exp(-|x|))*ln2 : 2 trans + 4 VALU (fma-folded)
    float e = __expf(-fabsf(x));
    return fmaf(__log2f(1.0f + e), 0.69314718056f, fmaxf(x, 0.0f));
}

// ---------------- prep: repack (both operands -> MFMA fragment order) + tproj, one dispatch ----
// Fragment order: P[tile = row/32][c = k/8 (48)][r = row&31][8 elems]. A wave's fragment
// load (lane l -> ((tile*48 + c)*32 + (l&31))*8, c differing by l>>5) is 1 KB fully
// coalesced. R10 proved this for the activation panel; R11 extends it to the weight
// panel, which lets the GEMM kernel drop LDS staging entirely.
#define REPACK_NB 2
#define REPACK_BLOCKS 1728
#define TPROJ_BLOCKS 336      /* 84 x 4 */
#define PREP_BLOCKS (REPACK_BLOCKS + TPROJ_BLOCKS)
__global__ __launch_bounds__(256) void prep(
        const float* __restrict__ x, const float* __restrict__ iv,
        const float* __restrict__ temb,
        const float* __restrict__ Wa, const float* __restrict__ Wi,
        const float* __restrict__ Wt,
        const float* __restrict__ tW3, const float* __restrict__ tb3,
        const float* __restrict__ tW2, const float* __restrict__ tb2,
        const float* __restrict__ tW1, const float* __restrict__ tb1,
        unsigned short* __restrict__ Abf /* Wbf follows contiguously */,
        float* __restrict__ tp3T, float* __restrict__ tp2T, float* __restrict__ tp1T) {
    __shared__ float se[32 * 64];
    const int tid = threadIdx.x;

    if (blockIdx.x < TPROJ_BLOCKS) {
        // ---- tproj part: tp3T[4096][128], tp2T[1024][128], tp1T[256][128] ----
        const int bx = blockIdx.x % 84;
        const int by = blockIdx.x / 84;
        const int tbase = by * 32;
        for (int i = tid; i < 32 * 64; i += 256) se[i] = temb[tbase * 64 + i];
        __syncthreads();
        const int j = bx * 64 + (tid >> 2);
        const float* W; const float* bias; float* outp; int jl;
        if      (j < 4096) { W = tW3; bias = tb3; outp = tp3T; jl = j; }
        else if (j < 5120) { W = tW2; bias = tb2; outp = tp2T; jl = j - 4096; }
        else               { W = tW1; bias = tb1; outp = tp1T; jl = j - 5120; }
        float4 wreg[16];
        const float4* wrow = (const float4*)(W + (size_t)jl * 64);
        #pragma unroll
        for (int k = 0; k < 16; ++k) wreg[k] = wrow[k];
        const float b = bias[jl];
        #pragma unroll
        for (int s = 0; s < 8; ++s) {
            const int tl = (tid & 3) + s * 4;
            const float4* e4 = (const float4*)&se[tl * 64];
            float a = b;
            #pragma unroll
            for (int k = 0; k < 16; ++k) {
                float4 e = e4[k];
                a += wreg[k].x * e.x + wreg[k].y * e.y + wreg[k].z * e.z + wreg[k].w * e.w;
            }
            outp[(size_t)jl * 128 + tbase + tl] = a;
        }
        return;
    }

    // ---- repack part: A=[x|iv|temb] then W=[Wa|Wi|Wt], both in fragment order ----
    const int stride = REPACK_BLOCKS * 256;
    const int tid0 = (blockIdx.x - TPROJ_BLOCKS) * 256 + tid;
    float4 f[REPACK_NB][2];
    #pragma unroll
    for (int c = 0; c < REPACK_NB; ++c) {
        const int idx = tid0 + c * stride;
        const bool isA = idx < 98304;
        const int widx = isA ? idx : idx - 98304;
        const int row = widx / 48;
        const int kk  = (widx % 48) * 8;
        const float* p0 = isA ? (x    + (size_t)row * 256) : (Wa + (size_t)row * 256);
        const float* p1 = isA ? (iv   + (size_t)row * 64)  : (Wi + (size_t)row * 64);
        const float* p2 = isA ? (temb + (size_t)(row & 127) * 64) : (Wt + (size_t)row * 64);
        const float* src = (kk < 256) ? (p0 + kk) : ((kk < 320) ? (p1 + kk - 256) : (p2 + kk - 320));
        f[c][0] = ((const float4*)src)[0];
        f[c][1] = ((const float4*)src)[1];
    }
    #pragma unroll
    for (int c = 0; c < REPACK_NB; ++c) {
        const int idx = tid0 + c * stride;
        const bool isA = idx < 98304;
        const int widx = isA ? idx : idx - 98304;
        const int row = widx / 48;
        const int ch  = widx % 48;
        // fragment-order permutation (same for both panels; W offset by the A panel size)
        const size_t dst = (size_t)(isA ? 0 : 98304) +
                           (size_t)(((row >> 5) * 48 + ch) * 32 + (row & 31));
        u16x8 o;
        o[0] = f2bf(f[c][0].x); o[1] = f2bf(f[c][0].y); o[2] = f2bf(f[c][0].z); o[3] = f2bf(f[c][0].w);
        o[4] = f2bf(f[c][1].x); o[5] = f2bf(f[c][1].y); o[6] = f2bf(f[c][1].z); o[7] = f2bf(f[c][1].w);
        *(u16x8*)(Abf + dst * 8) = o;
    }
}

// ---------------- main: transposed GEMM (M=16384 nodes, N=2048 bt, K=384) + tree ----------------
// 32x32x16 MFMA, 128x128 tile per block (4 waves: wr = node half, wc = time half).
// R11: ZERO LDS, ZERO barriers. Both operands pre-permuted to fragment order, so each
//      fragment is one coalesced 1 KB wave-load global->VGPR (L1/L2-resident panels,
//      wave pairs share fragments -> L1 hits). K-loop = 24 x {4 loads + 4 MFMAs}, fully
//      unrolled; the compiler software-pipelines freely with counted vmcnt (no barrier
//      drains -- the structural stall of R7-R10 is gone).
// C-layout (m74/m101): col = lane&31 (time), row = (reg&3) + 8*(reg>>2) + 4*(lane>>5).
__global__ __launch_bounds__(256, 3)
void fused_gemm_tree(const unsigned short* __restrict__ Wf,    // A-operand, fragment order
                     const unsigned short* __restrict__ Af,    // B-operand, fragment order
                     const float* __restrict__ ba,
                     const float* __restrict__ tp3T, const float* __restrict__ tp2T,
                     const float* __restrict__ tp1T,
                     const float* __restrict__ w3, const float* __restrict__ w2,
                     const float* __restrict__ w1,
                     float* __restrict__ out) {
    const int tid  = threadIdx.x;
    const int wave = tid >> 6;
    const int lane = tid & 63;
    const int wr = wave >> 1;          // node half: n = blockIdx.x*2 + wr
    const int wc = wave & 1;           // time half
    const int lane31 = lane & 31;
    const int h = lane >> 5;

    const int node0 = blockIdx.x * 128;
    const int m0    = blockIdx.y * 128;

    // acc init = leaf bias (ba folded into the MFMA C operand)
    f32x16 acc[2][2];
    #pragma unroll
    for (int fm = 0; fm < 2; ++fm)
        #pragma unroll
        for (int s2 = 0; s2 < 4; ++s2) {
            const float4 b4 = *(const float4*)&ba[node0 + wr * 64 + fm * 32 + 8 * s2 + 4 * h];
            #pragma unroll
            for (int l = 0; l < 4; ++l) {
                acc[fm][0][s2 * 4 + l] = ((const float*)&b4)[l];
                acc[fm][1][s2 * 4 + l] = ((const float*)&b4)[l];
            }
        }

    // fragment base pointers: P[tile][c][r][8]; lane reads chunk c+h at r=lane31
    const int ntBase = blockIdx.x * 4 + wr * 2;     // W tiles (fm = 0,1)
    const int mtBase = blockIdx.y * 4 + wc * 2;     // B tiles (cf = 0,1)
    const unsigned short* aC0 = Wf + (((size_t)(ntBase + 0) * 48 + h) * 32 + lane31) * 8;
    const unsigned short* aC1 = Wf + (((size_t)(ntBase + 1) * 48 + h) * 32 + lane31) * 8;
    const unsigned short* bC0 = Af + (((size_t)(mtBase + 0) * 48 + h) * 32 + lane31) * 8;
    const unsigned short* bC1 = Af + (((size_t)(mtBase + 1) * 48 + h) * 32 + lane31) * 8;

    #pragma unroll
    for (int c = 0; c < 48; c += 2) {              // K=16 per step, 24 steps
        const size_t off = (size_t)c * 256;        // chunk stride = 32 rows * 8 elems
        bf16x8 a0 = *(const bf16x8*)(aC0 + off);
        bf16x8 a1 = *(const bf16x8*)(aC1 + off);
        bf16x8 b0 = *(const bf16x8*)(bC0 + off);
        bf16x8 b1 = *(const bf16x8*)(bC1 + off);
        acc[0][0] = __builtin_amdgcn_mfma_f32_32x32x16_bf16(a0, b0, acc[0][0], 0, 0, 0);
        acc[0][1] = __builtin_amdgcn_mfma_f32_32x32x16_bf16(a0, b1, acc[0][1], 0, 0, 0);
        acc[1][0] = __builtin_amdgcn_mfma_f32_32x32x16_bf16(a1, b0, acc[1][0], 0, 0, 0);
        acc[1][1] = __builtin_amdgcn_mfma_f32_32x32x16_bf16(a1, b1, acc[1][1], 0, 0, 0);
    }

    // ---- epilogue: softplus + 4/4/4 tree ----
    const int n = blockIdx.x * 2 + wr;
    const int t0 = wc * 64 + lane31;                   // + cf*32 -> t

    float4 w3v[2][4];
    #pragma unroll
    for (int fm = 0; fm < 2; ++fm)
        #pragma unroll
        for (int s2 = 0; s2 < 4; ++s2)
            w3v[fm][s2] = *(const float4*)&w3[n * 64 + fm * 32 + 8 * s2 + 4 * h];

    float w2v[4][2], w1v[4];                            // [i][s2b] , jj = 2*s2b + h
    #pragma unroll
    for (int i = 0; i < 4; ++i) {
        #pragma unroll
        for (int s2b = 0; s2b < 2; ++s2b)
            w2v[i][s2b] = w2[n * 16 + i * 4 + 2 * s2b + h];
        w1v[i] = w1[n * 4 + i];
    }
    float tp3v[2][2][4];                                // needed for BOTH cf (feeds shuffles)
    #pragma unroll
    for (int fm = 0; fm < 2; ++fm)
        #pragma unroll
        for (int cf = 0; cf < 2; ++cf) {
            const int t = t0 + cf * 32;
            #pragma unroll
            for (int s2 = 0; s2 < 4; ++s2) {
                const int i  = fm * 2 + (s2 >> 1);
                const int jj = 2 * (s2 & 1) + h;
                tp3v[fm][cf][s2] = tp3T[(size_t)((n * 4 + i) * 4 + jj) * 128 + t];
            }
        }
    // post-shuffle work only needs this half's own time column (cf = h)
    const int th = t0 + h * 32;
    float tp2h[2][2];                                   // [fm][b] at cf=h
    #pragma unroll
    for (int fm = 0; fm < 2; ++fm)
        #pragma unroll
        for (int b = 0; b < 2; ++b)
            tp2h[fm][b] = tp2T[(size_t)(n * 4 + fm * 2 + b) * 128 + th];
    const float tp1h = tp1T[(size_t)n * 128 + th];

    float s1h = 0.0f;
    #pragma unroll
    for (int fm = 0; fm < 2; ++fm) {
        #pragma unroll
        for (int b = 0; b < 2; ++b) {                   // i = fm*2 + b
            float cs[2];
            #pragma unroll
            for (int cf = 0; cf < 2; ++cf) {            // level-3: both cf (shuffle inputs)
                float c = 0.0f;
                #pragma unroll
                for (int s2b = 0; s2b < 2; ++s2b) {
                    const int s2 = 2 * b + s2b;
                    float p3 = 0.0f;
                    const float* wv = (const float*)&w3v[fm][s2];
                    #pragma unroll
                    for (int l = 0; l < 4; ++l) {
                        float a0 = softplus_f(acc[fm][cf][s2 * 4 + l]);   // ba already in acc
                        p3 = fmaf(a0, wv[l], p3);
                    }
                    float a3 = softplus_f(p3 + tp3v[fm][cf][s2]);
                    c = fmaf(a3, w2v[fm * 2 + b][s2b], c);
                }
                cs[cf] = c;
            }
            const float Q0 = cs[0] + __shfl_xor(cs[0], 32);   // jj-sum across halves
            const float Q1 = cs[1] + __shfl_xor(cs[1], 32);
            const float Qh = h ? Q1 : Q0;
            const float a2 = softplus_f(Qh + tp2h[fm][b]);
            s1h = fmaf(a2, w1v[fm * 2 + b], s1h);
        }
    }
    // half h stores its own t-column: 64 unique (t, n) per wave
    out[(size_t)(m0 + th) * 256 + n] = softplus_f(s1h + tp1h);
}

// ---------------- launcher ----------------
extern "C" void kernel_launch(void* const* d_in, const int* in_sizes, int n_in,
                              void* d_out, int out_size, void* d_ws, size_t ws_size,
                              hipStream_t stream) {
    const float* x    = (const float*)d_in[0];
    const float* temb = (const float*)d_in[1];
    const float* iv   = (const float*)d_in[2];
    const float* Wa   = (const float*)d_in[3];
    const float* ba   = (const float*)d_in[4];
    const float* Wt   = (const float*)d_in[5];
    const float* Wi   = (const float*)d_in[6];
    const float* w3   = (const float*)d_in[7];
    const float* tW3  = (const float*)d_in[8];
    const float* tb3  = (const float*)d_in[9];
    const float* w2   = (const float*)d_in[10];
    const float* tW2  = (const float*)d_in[11];
    const float* tb2  = (const float*)d_in[12];
    const float* w1   = (const float*)d_in[13];
    const float* tW1  = (const float*)d_in[14];
    const float* tb1  = (const float*)d_in[15];
    float* out = (float*)d_out;

    char* ws = (char*)d_ws;
    unsigned short* Abf = (unsigned short*)(ws);              //  activation panel, fragment order
    unsigned short* Wbf = (unsigned short*)(ws + 1572864);    //  weight panel, fragment order
    float* tp3T = (float*)(ws + 14155776);                    //  [4096][128]
    float* tp2T = (float*)(ws + 16252928);                    //  [1024][128]
    float* tp1T = (float*)(ws + 16777216);                    //  [256][128]

    prep<<<dim3(PREP_BLOCKS), dim3(256), 0, stream>>>(x, iv, temb, Wa, Wi, Wt,
                                                      tW3, tb3, tW2, tb2, tW1, tb1,
                                                      Abf, tp3T, tp2T, tp1T);
    fused_gemm_tree<<<dim3(128, 16), dim3(256), 0, stream>>>(Wbf, Abf, ba, tp3T, tp2T, tp1T,
                                                             w3, w2, w1, out);
}

// Round 6
// 143.786 us; speedup vs baseline: 1.2066x; 1.2066x over previous
//
#include <hip/hip_runtime.h>

// ---------------- types / helpers ----------------
typedef __attribute__((ext_vector_type(16))) float f32x16;
typedef __attribute__((ext_vector_type(8))) __bf16 bf16x8;
typedef __attribute__((ext_vector_type(8))) unsigned short u16x8;

__device__ __forceinline__ unsigned short f2bf(float f) {
    unsigned int u = __float_as_uint(f);
    u += 0x7fffu + ((u >> 16) & 1u);       // RTNE
    return (unsigned short)(u >> 16);
}

__device__ __forceinline__ float softplus_f(float x) {
    // max(x,0) + log2(1+exp(-|x|))*ln2 : 2 trans + 4 VALU (fma-folded)
    float e = __expf(-fabsf(x));
    return fmaf(__log2f(1.0f + e), 0.69314718056f, fmaxf(x, 0.0f));
}

typedef __attribute__((address_space(3))) void lds_void_t;
typedef __attribute__((address_space(1))) void glb_void_t;

__device__ __forceinline__ void load16_to_lds(const void* g, const void* l) {
    __builtin_amdgcn_global_load_lds((glb_void_t*)(unsigned long long)g,
                                     (lds_void_t*)(unsigned int)(unsigned long long)l,
                                     16, 0, 0);
}

// ---------------- prep: repack + tproj in one dispatch ----------------
// Activation panel (GEMM B-operand): MFMA FRAGMENT order (R10-proven):
//   B'[tile = row/32][c = k/8 (48)][r = row&31][8 elems] -> 1 KB coalesced wave frag-loads.
// Weight panel (GEMM A-operand): ROW-MAJOR (R11's fragment-order W + no-LDS regressed:
//   FETCH 13.8->44 MB, WRITE 8->49 MB; W must stream through LDS, staged once per block).
#define REPACK_NB 2
#define REPACK_BLOCKS 1728
#define TPROJ_BLOCKS 336      /* 84 x 4 */
#define PREP_BLOCKS (REPACK_BLOCKS + TPROJ_BLOCKS)
__global__ __launch_bounds__(256) void prep(
        const float* __restrict__ x, const float* __restrict__ iv,
        const float* __restrict__ temb,
        const float* __restrict__ Wa, const float* __restrict__ Wi,
        const float* __restrict__ Wt,
        const float* __restrict__ tW3, const float* __restrict__ tb3,
        const float* __restrict__ tW2, const float* __restrict__ tb2,
        const float* __restrict__ tW1, const float* __restrict__ tb1,
        unsigned short* __restrict__ Abf /* Wbf follows contiguously */,
        float* __restrict__ tp3T, float* __restrict__ tp2T, float* __restrict__ tp1T) {
    __shared__ float se[32 * 64];
    const int tid = threadIdx.x;

    if (blockIdx.x < TPROJ_BLOCKS) {
        // ---- tproj part: tp3T[4096][128], tp2T[1024][128], tp1T[256][128] ----
        const int bx = blockIdx.x % 84;
        const int by = blockIdx.x / 84;
        const int tbase = by * 32;
        for (int i = tid; i < 32 * 64; i += 256) se[i] = temb[tbase * 64 + i];
        __syncthreads();
        const int j = bx * 64 + (tid >> 2);
        const float* W; const float* bias; float* outp; int jl;
        if      (j < 4096) { W = tW3; bias = tb3; outp = tp3T; jl = j; }
        else if (j < 5120) { W = tW2; bias = tb2; outp = tp2T; jl = j - 4096; }
        else               { W = tW1; bias = tb1; outp = tp1T; jl = j - 5120; }
        float4 wreg[16];
        const float4* wrow = (const float4*)(W + (size_t)jl * 64);
        #pragma unroll
        for (int k = 0; k < 16; ++k) wreg[k] = wrow[k];
        const float b = bias[jl];
        #pragma unroll
        for (int s = 0; s < 8; ++s) {
            const int tl = (tid & 3) + s * 4;
            const float4* e4 = (const float4*)&se[tl * 64];
            float a = b;
            #pragma unroll
            for (int k = 0; k < 16; ++k) {
                float4 e = e4[k];
                a += wreg[k].x * e.x + wreg[k].y * e.y + wreg[k].z * e.z + wreg[k].w * e.w;
            }
            outp[(size_t)jl * 128 + tbase + tl] = a;
        }
        return;
    }

    // ---- repack part: A=[x|iv|temb] (fragment order), W=[Wa|Wi|Wt] (row-major) ----
    const int stride = REPACK_BLOCKS * 256;
    const int tid0 = (blockIdx.x - TPROJ_BLOCKS) * 256 + tid;
    float4 f[REPACK_NB][2];
    #pragma unroll
    for (int c = 0; c < REPACK_NB; ++c) {
        const int idx = tid0 + c * stride;
        const bool isA = idx < 98304;
        const int widx = isA ? idx : idx - 98304;
        const int row = widx / 48;
        const int kk  = (widx % 48) * 8;
        const float* p0 = isA ? (x    + (size_t)row * 256) : (Wa + (size_t)row * 256);
        const float* p1 = isA ? (iv   + (size_t)row * 64)  : (Wi + (size_t)row * 64);
        const float* p2 = isA ? (temb + (size_t)(row & 127) * 64) : (Wt + (size_t)row * 64);
        const float* src = (kk < 256) ? (p0 + kk) : ((kk < 320) ? (p1 + kk - 256) : (p2 + kk - 320));
        f[c][0] = ((const float4*)src)[0];
        f[c][1] = ((const float4*)src)[1];
    }
    #pragma unroll
    for (int c = 0; c < REPACK_NB; ++c) {
        const int idx = tid0 + c * stride;
        const bool isA = idx < 98304;
        const int widx = isA ? idx : idx - 98304;
        const int row = widx / 48;
        const int ch  = widx % 48;
        // A panel: fragment-order permutation; W panel: linear (row-major)
        const size_t dst = isA ? (size_t)(((row >> 5) * 48 + ch) * 32 + (row & 31))
                               : (size_t)idx;
        u16x8 o;
        o[0] = f2bf(f[c][0].x); o[1] = f2bf(f[c][0].y); o[2] = f2bf(f[c][0].z); o[3] = f2bf(f[c][0].w);
        o[4] = f2bf(f[c][1].x); o[5] = f2bf(f[c][1].y); o[6] = f2bf(f[c][1].z); o[7] = f2bf(f[c][1].w);
        *(u16x8*)(Abf + dst * 8) = o;
    }
}

// ---------------- main: transposed GEMM (M=16384 nodes, N=2048 bt, K=384) + tree ----------------
// 32x32x16 MFMA, 128x128 tile, BK=64. R12 = R10 (A staged in LDS via global_load_lds,
// XOR-8 swizzled source; B direct coalesced fragment loads from the fragment-ordered
// panel) + T3 "minimum 2-phase" schedule:
//   iter it: {load B(it) frags FIRST (so b-use waitcnt is a counted vmcnt, not a drain);
//             prefetch A(it+1) into sW[(it+1)&1]; compute on sW[it&1]; ONE barrier}.
// The end-of-iter barrier's vmcnt(0) drain overlaps the compute that just ran, instead
// of exposing the full staging latency (R7-R10's stage->drain->compute did, 6x/block).
// Race check: buffer b is re-staged in iter it+1 only after the iter-it barrier, by
// which point all waves finished reading it; each wave's staging is drained by its own
// barrier waitcnt before the next ds_read. Single barrier per iter is sufficient.
// C-layout (m74/m101): col = lane&31 (time), row = (reg&3) + 8*(reg>>2) + 4*(lane>>5).
__global__ __launch_bounds__(256, 3)
void fused_gemm_tree(const unsigned short* __restrict__ Wbf,   // A-operand [16384][384] row-major
                     const unsigned short* __restrict__ Abf,   // B-operand, fragment order
                     const float* __restrict__ ba,
                     const float* __restrict__ tp3T, const float* __restrict__ tp2T,
                     const float* __restrict__ tp1T,
                     const float* __restrict__ w3, const float* __restrict__ w2,
                     const float* __restrict__ w1,
                     float* __restrict__ out) {
    __shared__ unsigned short sW[2][128 * 64];   // 2 x 16 KB double buffer (A only)

    const int tid  = threadIdx.x;
    const int wave = tid >> 6;
    const int lane = tid & 63;
    const int wr = wave >> 1;          // node half: n = blockIdx.x*2 + wr
    const int wc = wave & 1;           // time half
    const int lane31 = lane & 31;
    const int h = lane >> 5;

    const int node0 = blockIdx.x * 128;
    const int m0    = blockIdx.y * 128;

    // acc init = leaf bias (ba folded into the MFMA C operand)
    f32x16 acc[2][2];
    #pragma unroll
    for (int fm = 0; fm < 2; ++fm)
        #pragma unroll
        for (int s2 = 0; s2 < 4; ++s2) {
            const float4 b4 = *(const float4*)&ba[node0 + wr * 64 + fm * 32 + 8 * s2 + 4 * h];
            #pragma unroll
            for (int l = 0; l < 4; ++l) {
                acc[fm][0][s2 * 4 + l] = ((const float*)&b4)[l];
                acc[fm][1][s2 * 4 + l] = ((const float*)&b4)[l];
            }
        }

    const unsigned short* aBase = Wbf + (size_t)node0 * 384;
    const int wrow0 = wr * 64 + lane31;        // A rows: + fm*32

    // B fragment base pointers: B'[tile][c][r][8]; this wave's tiles = m0/32 + wc*2 + cf
    const int mtBase = blockIdx.y * 4 + wc * 2;
    const unsigned short* bC0 = Abf + (((size_t)(mtBase + 0) * 48 + h) * 32 + lane31) * 8;
    const unsigned short* bC1 = Abf + (((size_t)(mtBase + 1) * 48 + h) * 32 + lane31) * 8;

    // per-thread staging geometry (constant across K-steps)
    int srow[4], skch[4];
    #pragma unroll
    for (int rr = 0; rr < 4; ++rr) {
        const int p = rr * 256 + tid;          // chunk (row = p>>3, c = p&7)
        srow[rr] = p >> 3;
        skch[rr] = (p & 7) ^ (srow[rr] & 7);   // XOR-8 swizzled source
    }
    #define STAGE_A(K0, BB)                                                        \
        _Pragma("unroll")                                                          \
        for (int rr = 0; rr < 4; ++rr)                                             \
            load16_to_lds(aBase + (size_t)srow[rr] * 384 + (K0) + skch[rr] * 8,    \
                          &sW[BB][(size_t)(rr * 256 + wave * 64) * 8]);

    // prologue: stage K-step 0 into buffer 0
    STAGE_A(0, 0);
    __syncthreads();

    #pragma unroll
    for (int it = 0; it < 6; ++it) {
        const int k0 = it * 64;
        // B fragments for THIS step -- issued before the staging so the compiler's
        // waitcnt before b-use counts only the 4 outstanding global_load_lds.
        bf16x8 bfr[2][4];
        const int cbase = k0 >> 3;
        #pragma unroll
        for (int s = 0; s < 4; ++s) {
            bfr[0][s] = *(const bf16x8*)(bC0 + (size_t)(cbase + 2 * s) * 256);
            bfr[1][s] = *(const bf16x8*)(bC1 + (size_t)(cbase + 2 * s) * 256);
        }
        // prefetch next A tile into the other buffer (latency hidden under compute)
        if (it < 5) { STAGE_A(k0 + 64, (it + 1) & 1); }
        // compute on current buffer
        #pragma unroll
        for (int s = 0; s < 4; ++s) {
            const int kc = s * 2 + h;
            const int slot = (kc ^ (lane & 7)) * 8;    // fm-invariant read slot
            bf16x8 af[2];
            #pragma unroll
            for (int fm = 0; fm < 2; ++fm)
                af[fm] = *(const bf16x8*)&sW[it & 1][(wrow0 + fm * 32) * 64 + slot];
            acc[0][0] = __builtin_amdgcn_mfma_f32_32x32x16_bf16(af[0], bfr[0][s], acc[0][0], 0, 0, 0);
            acc[0][1] = __builtin_amdgcn_mfma_f32_32x32x16_bf16(af[0], bfr[1][s], acc[0][1], 0, 0, 0);
            acc[1][0] = __builtin_amdgcn_mfma_f32_32x32x16_bf16(af[1], bfr[0][s], acc[1][0], 0, 0, 0);
            acc[1][1] = __builtin_amdgcn_mfma_f32_32x32x16_bf16(af[1], bfr[1][s], acc[1][1], 0, 0, 0);
        }
        if (it < 5) __syncthreads();   // drains the prefetch; syncs buffer reuse
    }

    // ---- epilogue: softplus + 4/4/4 tree ----
    const int n = blockIdx.x * 2 + wr;
    const int t0 = wc * 64 + lane31;                   // + cf*32 -> t

    float4 w3v[2][4];
    #pragma unroll
    for (int fm = 0; fm < 2; ++fm)
        #pragma unroll
        for (int s2 = 0; s2 < 4; ++s2)
            w3v[fm][s2] = *(const float4*)&w3[n * 64 + fm * 32 + 8 * s2 + 4 * h];

    float w2v[4][2], w1v[4];                            // [i][s2b] , jj = 2*s2b + h
    #pragma unroll
    for (int i = 0; i < 4; ++i) {
        #pragma unroll
        for (int s2b = 0; s2b < 2; ++s2b)
            w2v[i][s2b] = w2[n * 16 + i * 4 + 2 * s2b + h];
        w1v[i] = w1[n * 4 + i];
    }
    float tp3v[2][2][4];                                // needed for BOTH cf (feeds shuffles)
    #pragma unroll
    for (int fm = 0; fm < 2; ++fm)
        #pragma unroll
        for (int cf = 0; cf < 2; ++cf) {
            const int t = t0 + cf * 32;
            #pragma unroll
            for (int s2 = 0; s2 < 4; ++s2) {
                const int i  = fm * 2 + (s2 >> 1);
                const int jj = 2 * (s2 & 1) + h;
                tp3v[fm][cf][s2] = tp3T[(size_t)((n * 4 + i) * 4 + jj) * 128 + t];
            }
        }
    // post-shuffle work only needs this half's own time column (cf = h)
    const int th = t0 + h * 32;
    float tp2h[2][2];                                   // [fm][b] at cf=h
    #pragma unroll
    for (int fm = 0; fm < 2; ++fm)
        #pragma unroll
        for (int b = 0; b < 2; ++b)
            tp2h[fm][b] = tp2T[(size_t)(n * 4 + fm * 2 + b) * 128 + th];
    const float tp1h = tp1T[(size_t)n * 128 + th];

    float s1h = 0.0f;
    #pragma unroll
    for (int fm = 0; fm < 2; ++fm) {
        #pragma unroll
        for (int b = 0; b < 2; ++b) {                   // i = fm*2 + b
            float cs[2];
            #pragma unroll
            for (int cf = 0; cf < 2; ++cf) {            // level-3: both cf (shuffle inputs)
                float c = 0.0f;
                #pragma unroll
                for (int s2b = 0; s2b < 2; ++s2b) {
                    const int s2 = 2 * b + s2b;
                    float p3 = 0.0f;
                    const float* wv = (const float*)&w3v[fm][s2];
                    #pragma unroll
                    for (int l = 0; l < 4; ++l) {
                        float a0 = softplus_f(acc[fm][cf][s2 * 4 + l]);   // ba already in acc
                        p3 = fmaf(a0, wv[l], p3);
                    }
                    float a3 = softplus_f(p3 + tp3v[fm][cf][s2]);
                    c = fmaf(a3, w2v[fm * 2 + b][s2b], c);
                }
                cs[cf] = c;
            }
            const float Q0 = cs[0] + __shfl_xor(cs[0], 32);   // jj-sum across halves
            const float Q1 = cs[1] + __shfl_xor(cs[1], 32);
            const float Qh = h ? Q1 : Q0;
            const float a2 = softplus_f(Qh + tp2h[fm][b]);
            s1h = fmaf(a2, w1v[fm * 2 + b], s1h);
        }
    }
    // half h stores its own t-column: 64 unique (t, n) per wave
    out[(size_t)(m0 + th) * 256 + n] = softplus_f(s1h + tp1h);
}

// ---------------- launcher ----------------
extern "C" void kernel_launch(void* const* d_in, const int* in_sizes, int n_in,
                              void* d_out, int out_size, void* d_ws, size_t ws_size,
                              hipStream_t stream) {
    const float* x    = (const float*)d_in[0];
    const float* temb = (const float*)d_in[1];
    const float* iv   = (const float*)d_in[2];
    const float* Wa   = (const float*)d_in[3];
    const float* ba   = (const float*)d_in[4];
    const float* Wt   = (const float*)d_in[5];
    const float* Wi   = (const float*)d_in[6];
    const float* w3   = (const float*)d_in[7];
    const float* tW3  = (const float*)d_in[8];
    const float* tb3  = (const float*)d_in[9];
    const float* w2   = (const float*)d_in[10];
    const float* tW2  = (const float*)d_in[11];
    const float* tb2  = (const float*)d_in[12];
    const float* w1   = (const float*)d_in[13];
    const float* tW1  = (const float*)d_in[14];
    const float* tb1  = (const float*)d_in[15];
    float* out = (float*)d_out;

    char* ws = (char*)d_ws;
    unsigned short* Abf = (unsigned short*)(ws);              //  activation panel, fragment order
    unsigned short* Wbf = (unsigned short*)(ws + 1572864);    //  weight panel, row-major
    float* tp3T = (float*)(ws + 14155776);                    //  [4096][128]
    float* tp2T = (float*)(ws + 16252928);                    //  [1024][128]
    float* tp1T = (float*)(ws + 16777216);                    //  [256][128]

    prep<<<dim3(PREP_BLOCKS), dim3(256), 0, stream>>>(x, iv, temb, Wa, Wi, Wt,
                                                      tW3, tb3, tW2, tb2, tW1, tb1,
                                                      Abf, tp3T, tp2T, tp1T);
    fused_gemm_tree<<<dim3(128, 16), dim3(256), 0, stream>>>(Wbf, Abf, ba, tp3T, tp2T, tp1T,
                                                             w3, w2, w1, out);
}